// Round 15
// baseline (185.715 us; speedup 1.0000x reference)
//
#include <hip/hip_runtime.h>
#include <math.h>

#define DEVFN __device__ __forceinline__

typedef __bf16 bf16x8 __attribute__((ext_vector_type(8)));
typedef float f32x4 __attribute__((ext_vector_type(4)));

constexpr int T_ = 32;
constexpr int HW = 128;
constexpr int C1IN = 1928;        // cnn1 input channels
constexpr int C1 = 964;

DEVFN float sigm(float x) { return 1.0f / (1.0f + __expf(-x)); }
DEVFN float tanhfast(float x) { return 2.0f / (1.0f + __expf(-2.0f * x)) - 1.0f; }

DEVFN ushort f2b(float v) {       // fp32 -> bf16 (RNE)
    union { float f; unsigned u; } x; x.f = v;
    unsigned r = x.u + 0x7fffu + ((x.u >> 16) & 1u);
    return (ushort)(r >> 16);
}

// async DMA global->LDS, 16B per lane (r8 lesson: zero staging VGPRs).
DEVFN void gload16(const ushort* g, ushort* l) {
    __builtin_amdgcn_global_load_lds(
        (const __attribute__((address_space(1))) unsigned int*)g,
        (__attribute__((address_space(3))) unsigned int*)l, 16, 0, 0);
}

// ---------------------------------------------------------------------------
// k_front: union grid of INDEPENDENT work (parallelism-preserving fusion):
//   blocks [0,5533):      weight prep A2/A3/A4/whhT
//   blocks [5533,5774):   wsum (4 oc/blk, wave-reduce)
//   blocks [5774,6030):   sa (n, oc)
//   blocks [6030,9230):   sca: per-(n, o-quad) block recomputes conv_con+
//                         relu+pool into LDS (cheap VALU; replay ch0 L2-hot),
//                         then fc_con wave-reduce -> sca[n][o]. Replaces the
//                         separate k_sca_fc dispatch + yb round-trip (r14
//                         datapoint: one width-preserving boundary ~= 3.7us).
__global__ void k_front(const float* __restrict__ replay, const float* __restrict__ wc,
                        const float* __restrict__ bc, const float* __restrict__ fcw,
                        const float* __restrict__ fcb, const float* __restrict__ w1,
                        const float* __restrict__ w2, const float* __restrict__ w3,
                        const float* __restrict__ w4, const float* __restrict__ whh,
                        float* __restrict__ sca, float* __restrict__ wsum,
                        float* __restrict__ sa, ushort* __restrict__ A2,
                        ushort* __restrict__ A3, ushort* __restrict__ A4,
                        float* __restrict__ whhT) {
    const int bid = blockIdx.x;
    const int tx = threadIdx.x;
    constexpr int N2 = 2 * 512 * 1024;
    constexpr int N3 = 2 * 256 * 512;
    constexpr int N4 = 2 * 128 * 256;
    __shared__ __align__(16) float ys[961];
    if (bid < 5533) {
        const int idx = bid * 256 + tx;
        if (idx < N2) {
            const int kw = idx >> 19;
            const int r = idx & 524287;
            const int oc = r >> 10, ic = r & 1023;
            const float v = (oc < 482 && ic < 964) ? w2[(size_t)oc * 1928 + ic * 2 + kw] : 0.f;
            A2[idx] = f2b(v);
        } else if (idx < N2 + N3) {
            const int j = idx - N2;
            const int kw = j >> 17;
            const int r = j & 131071;
            const int oc = r >> 9, ic = r & 511;
            const float v = (oc < 241 && ic < 482) ? w3[(size_t)oc * 964 + ic * 2 + kw] : 0.f;
            A3[j] = f2b(v);
        } else if (idx < N2 + N3 + N4) {
            const int j = idx - (N2 + N3);
            const int kw = j >> 15;
            const int r = j & 32767;
            const int oc = r >> 8, ic = r & 255;
            const float v = (oc < 100 && ic < 241) ? w4[(size_t)oc * 482 + ic * 2 + kw] : 0.f;
            A4[j] = f2b(v);
        } else {
            const int j = idx - (N2 + N3 + N4);
            if (j < 40000) {
                const int m = j / 400, p = j - m * 400;
                const int go = (p & 3) * 100 + (p >> 2);
                whhT[m * 400 + p] = whh[go * 100 + m];
            }
        }
    } else if (bid < 5774) {
        const int oc = (bid - 5533) * 4 + (tx >> 6);       // < 964
        const int lane = tx & 63;
        const float* wr = w1 + (size_t)oc * C1IN * 2;
        float s0 = 0.f, s1 = 0.f;
        for (int ic = lane; ic < C1IN; ic += 64) {
            s0 += wr[ic * 2 + 0];
            s1 += wr[ic * 2 + 1];
        }
        #pragma unroll
        for (int off = 32; off > 0; off >>= 1) {
            s0 += __shfl_down(s0, off);
            s1 += __shfl_down(s1, off);
        }
        if (lane == 0) { wsum[oc * 2] = s0; wsum[oc * 2 + 1] = s1; }
    } else if (bid < 6030) {
        const int j = bid - 5774;                           // 0..255
        const int n = j >> 2;
        const int oc = (j & 3) * 256 + tx;
        if (oc < C1) {
            const int chs[5]    = {1, 3, 5, 6, 7};
            const int scales[5] = {4, 2, 5, 2, 1914};
            const int offs[5]   = {0, 4, 6, 11, 13};
            float s0 = 0.f, s1 = 0.f;
            #pragma unroll
            for (int k = 0; k < 5; ++k) {
                int v = (int)replay[((size_t)n * 8 + chs[k]) * HW * HW];
                if (v > scales[k]) v = 0;
                if (v >= 1 && v <= scales[k] - 1) {
                    const int ic = 1 + offs[k] + v;
                    s0 += w1[((size_t)oc * C1IN + ic) * 2 + 0];
                    s1 += w1[((size_t)oc * C1IN + ic) * 2 + 1];
                }
            }
            sa[(n * C1 + oc) * 2 + 0] = s0;
            sa[(n * C1 + oc) * 2 + 1] = s1;
        }
    } else {
        // sca blocks: sid in [0,3200) = 64 samples x 50 output-quads
        const int sid = bid - 6030;
        const int n = sid / 50;
        const int o0 = (sid - n * 50) * 4;
        const float* x = replay + (size_t)n * 8 * HW * HW;  // channel 0
        float wr_[16];
        #pragma unroll
        for (int t = 0; t < 16; ++t) wr_[t] = wc[t];
        const float bcv = bc[0];
        for (int idx = tx; idx < 961; idx += 256) {
            const int i = idx / 31, j = idx % 31;
            float m = 0.0f;
            #pragma unroll
            for (int di = 0; di < 2; ++di)
            #pragma unroll
            for (int dj = 0; dj < 2; ++dj) {
                const int h0 = 2 * (2 * i + di), w0 = 2 * (2 * j + dj);
                float acc = bcv;
                #pragma unroll
                for (int p = 0; p < 4; ++p)
                #pragma unroll
                for (int q = 0; q < 4; ++q)
                    acc += x[(h0 + p) * HW + (w0 + q)] * wr_[p * 4 + q];
                m = fmaxf(m, fmaxf(acc, 0.0f));
            }
            ys[idx] = m;
        }
        __syncthreads();
        const int wid = tx >> 6, lane = tx & 63;
        const int o = o0 + wid;                             // < 200
        float acc = 0.f;
        for (int m = lane; m < 961; m += 64)
            acc += ys[m] * fcw[(size_t)o * 961 + m];
        #pragma unroll
        for (int off = 32; off > 0; off >>= 1) acc += __shfl_down(acc, off);
        if (lane == 0) sca[n * 200 + o] = acc + fcb[o];
    }
}

// ---------------------------------------------------------------------------
// cnn1 low-rank decomposition + relu + pool(1,2), writes Bt2 (transposed,
// bf16): Bt2[(n*100 + u)][oc] = p1[n][oc][u] for u<99; u=99 zero pad row.
template <int OCT>
__global__ void k_cnn1(const float* __restrict__ sca, const float* __restrict__ emb,
                       const float* __restrict__ w1, const float* __restrict__ b1,
                       const float* __restrict__ wsum, const float* __restrict__ sa,
                       ushort* __restrict__ Bt2) {
    const int n = blockIdx.x;
    const int ocBase = blockIdx.y * OCT;
    const int tx = threadIdx.x;
    __shared__ float ev[200], sv[200], dv[200];
    __shared__ float oscal[OCT][7];
    __shared__ float vals[OCT][100];
    for (int i = tx; i < 200; i += blockDim.x) {
        const float e0 = emb[i], e1 = emb[200 + i];
        ev[i] = e0;
        dv[i] = e1 - e0;
        sv[i] = sca[n * 200 + i] - e0;
    }
    for (int i = tx; i < OCT * 7; i += blockDim.x) {
        const int ocl = i / 7, f = i % 7;
        const int oc = ocBase + ocl;
        float v = 0.f;
        if (oc < C1) {
            switch (f) {
                case 0: v = wsum[oc * 2 + 0]; break;
                case 1: v = wsum[oc * 2 + 1]; break;
                case 2: v = b1[oc]; break;
                case 3: v = w1[(size_t)oc * C1IN * 2 + 0]; break;
                case 4: v = w1[(size_t)oc * C1IN * 2 + 1]; break;
                case 5: v = sa[(n * C1 + oc) * 2 + 0]; break;
                case 6: v = sa[(n * C1 + oc) * 2 + 1]; break;
            }
        }
        oscal[ocl][f] = v;
    }
    __syncthreads();
    for (int item = tx; item < OCT * 99; item += blockDim.x) {
        const int ocl = item / 99, u = item % 99;
        const int oc = ocBase + ocl;
        float res = 0.f;
        if (oc < C1) {
            const float ws0 = oscal[ocl][0], ws1 = oscal[ocl][1], bb = oscal[ocl][2];
            const float a0 = oscal[ocl][3], a1 = oscal[ocl][4];
            const float s0 = oscal[ocl][5], s1 = oscal[ocl][6];
            float r = -INFINITY;
            #pragma unroll
            for (int dw = 0; dw < 2; ++dw) {
                const int ww = 2 * u + dw;
                const float o = bb + ws0 * ev[ww] + ws1 * ev[ww + 1]
                                   + a0 * sv[ww] + a1 * sv[ww + 1]
                                   + s0 * dv[ww] + s1 * dv[ww + 1];
                r = fmaxf(r, o);
            }
            res = fmaxf(r, 0.0f);
        }
        vals[ocl][u] = res;
    }
    __syncthreads();
    // transposed write: OCT ocs x 100 rows
    for (int i = tx; i < OCT * 100; i += blockDim.x) {
        const int u = i >> 4, ocl = i & 15;
        const float v = (u < 99) ? vals[ocl][u] : 0.0f;
        Bt2[(size_t)(n * 100 + u) * 1024 + ocBase + ocl] = f2b(v);
    }
    if (n == 0 && ocBase == 0) {
        for (int i = tx; i < 1024; i += blockDim.x)
            Bt2[(size_t)6400 * 1024 + i] = 0;
    }
}

// ---------------------------------------------------------------------------
// Conv-GEMM (w-shift): C[m][r] = sum_k A0[m][k]*Bt[r][k] + A1[m][k]*Bt[r+1][k]
// Tile 64(M)x128(N), BK=64, 4 waves, global_load_lds staging, double-buffered
// LDS with COUNTED vmcnt pipeline (T4): tiles staged 2 deep; per K-step wait
// only for the tile about to be computed (wave0 issues 9 DMAs/stage, others 8
// -> per-wave immediates), raw s_barrier (no drain). Source-side XOR swizzle,
// bijective XCD swizzle.
//   OMODE 0: fp32 [n][OCREAL][NOUTW]; OMODE 2: bf16 transposed next-layer B.
template <int OCREAL, int WR, int WOUT, int KICP, int MPAD, int OMODE, int OSTR,
          bool POOL, int MT, int NTILES>
__global__ __launch_bounds__(256, 2) void k_gemm_conv(
    const ushort* __restrict__ A, const ushort* __restrict__ Bt,
    const float* __restrict__ bias, void* __restrict__ outv) {
    constexpr int BK = 64;
    constexpr int NT = KICP / BK;
    constexpr int NWG = MT * NTILES;
    constexpr int Qq = NWG / 8, Rr = NWG % 8;

    __shared__ __align__(16) ushort As0[2][4096];   // 64 rows x 64 (8 slabs)
    __shared__ __align__(16) ushort As1[2][4096];
    __shared__ __align__(16) ushort Bs[2][8704];    // 128(+1) rows (17 slabs)

    const int bid = blockIdx.x;
    const int xcd = bid & 7, rest = bid >> 3;
    const int base = (xcd < Rr) ? xcd * (Qq + 1) : Rr * (Qq + 1) + (xcd - Rr) * Qq;
    const int sid = base + rest;
    const int mBase = (sid % MT) * 64;
    const int nBase = (sid / MT) * 128;

    const int tx = threadIdx.x;
    const int wave = tx >> 6, lane = tx & 63;
    const int lr = lane & 15, lk = lane >> 4;
    const int r8 = lane >> 3;                        // within-slab row
    const int cx = (lane & 7) ^ r8;                  // swizzled source chunk
    const ushort* A1p = A + (size_t)MPAD * KICP;

    f32x4 acc[4][2] = {};

    auto STAGE = [&](int buf, int kt) {
        const int k0 = kt * BK + cx * 8;
        #pragma unroll
        for (int it = 0; it < 2; ++it) {
            const int s = wave + it * 4;             // slab 0..7
            const int row = s * 8 + r8;
            gload16(&A[(size_t)(mBase + row) * KICP + k0], &As0[buf][s * 512]);
            gload16(&A1p[(size_t)(mBase + row) * KICP + k0], &As1[buf][s * 512]);
        }
        #pragma unroll
        for (int it = 0; it < 4; ++it) {
            const int s = wave + it * 4;             // slab 0..15
            const int row = s * 8 + r8;
            gload16(&Bt[(size_t)(nBase + row) * KICP + k0], &Bs[buf][s * 512]);
        }
        if (wave == 0) {
            const int row = 128 + r8;                // strays inert in d_ws
            gload16(&Bt[(size_t)(nBase + row) * KICP + k0], &Bs[buf][16 * 512]);
        }
    };

    auto COMPUTE = [&](int cur) {
        #pragma unroll
        for (int ks = 0; ks < 2; ++ks) {
            bf16x8 a0[4], a1[4], b0[2], b1[2];
            #pragma unroll
            for (int i = 0; i < 4; ++i) {
                const int row = i * 16 + lr;
                const int col = (ks * 32 + lk * 8) ^ ((row & 7) << 3);
                a0[i] = *(const bf16x8*)&As0[cur][row * 64 + col];
                a1[i] = *(const bf16x8*)&As1[cur][row * 64 + col];
            }
            #pragma unroll
            for (int j = 0; j < 2; ++j) {
                const int row = wave * 32 + j * 16 + lr;
                const int col = (ks * 32 + lk * 8) ^ ((row & 7) << 3);
                b0[j] = *(const bf16x8*)&Bs[cur][row * 64 + col];
                const int row1 = row + 1;
                const int col1 = (ks * 32 + lk * 8) ^ ((row1 & 7) << 3);
                b1[j] = *(const bf16x8*)&Bs[cur][row1 * 64 + col1];
            }
            #pragma unroll
            for (int i = 0; i < 4; ++i)
                #pragma unroll
                for (int j = 0; j < 2; ++j) {
                    acc[i][j] = __builtin_amdgcn_mfma_f32_16x16x32_bf16(a0[i], b0[j], acc[i][j], 0, 0, 0);
                    acc[i][j] = __builtin_amdgcn_mfma_f32_16x16x32_bf16(a1[i], b1[j], acc[i][j], 0, 0, 0);
                }
        }
    };

    // 2-deep prologue
    STAGE(0, 0);
    if (NT > 1) STAGE(1, 1);
    #pragma unroll 1
    for (int kt = 0; kt < NT; ++kt) {
        const int cur = kt & 1;
        // wait for tile kt only (issued 2 steps ago); per-wave DMA count 9/8
        if (kt + 1 < NT) {
            if (wave == 0) asm volatile("s_waitcnt vmcnt(9)" ::: "memory");
            else           asm volatile("s_waitcnt vmcnt(8)" ::: "memory");
        } else {
            asm volatile("s_waitcnt vmcnt(0)" ::: "memory");
        }
        __builtin_amdgcn_sched_barrier(0);
        __builtin_amdgcn_s_barrier();                // tile kt resident block-wide
        COMPUTE(cur);
        __builtin_amdgcn_s_barrier();                // all reads of buf cur done
        if (kt + 2 < NT) STAGE(cur, kt + 2);         // overwrite cur, flies 2 steps
    }

    ushort* outb = (ushort*)outv;
    float*  outf = (float*)outv;
    constexpr int NOUTW = POOL ? (WOUT / 2) : WOUT;
    constexpr int WRN = NOUTW + 1;                   // rows/sample next layer
    constexpr int NVALID = WR * 64;
    #pragma unroll
    for (int i = 0; i < 4; ++i) {
        const int m0 = mBase + i * 16 + lk * 4;
        #pragma unroll
        for (int j = 0; j < 2; ++j) {
            const int r = nBase + wave * 32 + j * 16 + lr;
            const int n = r / WR, w = r - n * WR;
            #pragma unroll
            for (int reg = 0; reg < 4; ++reg) {
                const float v = acc[i][j][reg];
                const float vo = __shfl_xor(v, 1);
                const int m = m0 + reg;
                const bool lok = POOL ? ((lr & 1) == 0) : true;
                if (lok && (w < WOUT) && (m < OCREAL) && (r < NVALID)) {
                    const float pre = POOL ? fmaxf(v, vo) : v;
                    const float val = fmaxf(pre + bias[m], 0.0f);
                    const int wc = POOL ? (w >> 1) : w;
                    if (OMODE == 2)
                        outb[((size_t)(n * WRN + wc)) * OSTR + m] = f2b(val);
                    else
                        outf[((size_t)n * OCREAL + m) * NOUTW + wc] = val;
                }
            }
        }
    }
}

// ---------------------------------------------------------------------------
// k_seq_xg: fc_cnn + xg fused, one block per sample (64 blocks x 512 thr,
// width-preserving vs r11's 2-block trap). Phase A: seq[n][100] in LDS via
// 4-lanes-per-dot quad reduce. Phase B: xg (permuted gate layout) from LDS.
__global__ __launch_bounds__(512) void k_seq_xg(
    const float* __restrict__ z4, const float* __restrict__ fcnw,
    const float* __restrict__ fcnb, const float* __restrict__ wih,
    const float* __restrict__ bih, const float* __restrict__ bhh,
    float* __restrict__ xg) {
    const int n = blockIdx.x;
    const int tx = threadIdx.x;
    __shared__ __align__(16) float seqs[100];
    if (tx < 400) {
        const int o = tx >> 2, l = tx & 3;
        const float4* zr = (const float4*)(z4 + (size_t)n * 2300);
        const float4* wr = (const float4*)(fcnw + (size_t)o * 2300);
        float acc = 0.f;
        for (int m = l; m < 575; m += 4) {
            const float4 wv = wr[m];
            const float4 zv = zr[m];
            acc += wv.x * zv.x + wv.y * zv.y + wv.z * zv.z + wv.w * zv.w;
        }
        acc += __shfl_xor(acc, 1);
        acc += __shfl_xor(acc, 2);
        if (l == 0) seqs[o] = acc + fcnb[o];
    }
    __syncthreads();
    if (tx < 400) {
        const int p = tx;
        const int go = (p & 3) * 100 + (p >> 2);
        const float4* wr = (const float4*)(wih + (size_t)go * 100);
        const float4* s4 = (const float4*)seqs;
        float4 a = {0.f, 0.f, 0.f, 0.f};
        #pragma unroll
        for (int m = 0; m < 25; ++m) {
            const float4 wv = wr[m];
            const float4 sv = s4[m];
            a.x += wv.x * sv.x; a.y += wv.y * sv.y;
            a.z += wv.z * sv.z; a.w += wv.w * sv.w;
        }
        xg[n * 400 + p] = bih[go] + bhh[go] + a.x + a.y + a.z + a.w;
    }
}

// ---------------------------------------------------------------------------
// LSTM: one block per batch. Per-quad distributed activations (1 transc
// per thread per phase instead of 5), fast tanh via __expf, 4-way split
// accumulators (chain 100 -> 25), 448 threads (7 waves).
__global__ __launch_bounds__(448) void k_lstm(const float* __restrict__ xg,
                                              const float* __restrict__ whhT,
                                              const float* __restrict__ fw,
                                              const float* __restrict__ fb,
                                              float* __restrict__ outp) {
    const int bb = blockIdx.x;
    const int tx = threadIdx.x;
    __shared__ __align__(16) float hb[2][104];
    float wreg[100];
    if (tx < 400) {
        #pragma unroll
        for (int m = 0; m < 100; ++m) wreg[m] = whhT[m * 400 + tx];
    }
    float creg = 0.f;
    if (tx < 104) { hb[0][tx] = 0.f; hb[1][tx] = 0.f; }
    float xnext = (tx < 400) ? xg[(size_t)(bb * T_) * 400 + tx] : 0.f;
    __syncthreads();
    const int lane = tx & 63, base = lane & ~3;
    const int g = tx & 3;
    for (int t = 0; t < T_; ++t) {
        float act = 0.f;
        if (tx < 400) {
            float a0 = xnext, a1 = 0.f, a2 = 0.f, a3 = 0.f;
            if (t + 1 < T_) xnext = xg[(size_t)(bb * T_ + t + 1) * 400 + tx];
            const float4* h4 = (const float4*)&hb[t & 1][0];
            #pragma unroll
            for (int m4 = 0; m4 < 25; ++m4) {
                const float4 hv = h4[m4];
                a0 += hv.x * wreg[4 * m4 + 0];
                a1 += hv.y * wreg[4 * m4 + 1];
                a2 += hv.z * wreg[4 * m4 + 2];
                a3 += hv.w * wreg[4 * m4 + 3];
            }
            const float accv = (a0 + a1) + (a2 + a3);
            act = (g == 2) ? tanhfast(accv) : sigm(accv);  // own gate only
        }
        const float aI = __shfl(act, base + 0);
        const float aF = __shfl(act, base + 1);
        const float aG = __shfl(act, base + 2);
        const float aO = __shfl(act, base + 3);
        if (tx < 400) {
            const float cn = aF * creg + aI * aG;
            creg = cn;
            if (g == 0) hb[(t + 1) & 1][tx >> 2] = aO * tanhfast(cn);
        }
        __syncthreads();
    }
    if (tx < 2) {
        float acc = fb[tx];
        for (int j = 0; j < 100; ++j) acc += hb[0][j] * fw[tx * 100 + j];
        outp[bb * 2 + tx] = acc;
    }
}

// ---------------------------------------------------------------------------
extern "C" void kernel_launch(void* const* d_in, const int* in_sizes, int n_in,
                              void* d_out, int out_size, void* d_ws, size_t ws_size,
                              hipStream_t stream) {
    (void)in_sizes; (void)n_in; (void)out_size; (void)ws_size;
    const float* replay = (const float*)d_in[0];
    const float* emb    = (const float*)d_in[1];
    const float* ccw    = (const float*)d_in[2];
    const float* ccb    = (const float*)d_in[3];
    const float* fcw    = (const float*)d_in[4];
    const float* fcb    = (const float*)d_in[5];
    const float* w1     = (const float*)d_in[6];
    const float* b1     = (const float*)d_in[7];
    const float* w2     = (const float*)d_in[8];
    const float* b2     = (const float*)d_in[9];
    const float* w3     = (const float*)d_in[10];
    const float* b3     = (const float*)d_in[11];
    const float* w4     = (const float*)d_in[12];
    const float* b4     = (const float*)d_in[13];
    const float* fcnw   = (const float*)d_in[14];
    const float* fcnb   = (const float*)d_in[15];
    const float* wih    = (const float*)d_in[16];
    const float* whh    = (const float*)d_in[17];
    const float* bih    = (const float*)d_in[18];
    const float* bhh    = (const float*)d_in[19];
    const float* fow    = (const float*)d_in[20];
    const float* fob    = (const float*)d_in[21];

    float* ws = (float*)d_ws;
    float*  sca  = ws + 0;                      // 12800
    float*  wsum = ws + 12800;                  // 2048
    float*  sa   = ws + 14848;                  // 123392 -> 138240
    float*  xg   = ws + 138240;                 // 25600 -> 163840
    float*  whhT = ws + 163840;                 // 40000 -> 203840
    float*  z4   = ws + 203840;                 // 147200 -> 351040
    ushort* A2   = (ushort*)(ws + 351040);      // 524288 fl -> 875328
    ushort* A3   = (ushort*)(ws + 875328);      // 131072 fl -> 1006400
    ushort* A4   = (ushort*)(ws + 1006400);     // 32768 fl -> 1039168
    ushort* Bt2  = (ushort*)(ws + 1039168);     // 6401*1024 sh = 3277312 fl -> 4316480
    ushort* Bt3  = (ushort*)(ws + 4316480);     // 3216*512 sh = 823296 fl -> 5139776
    ushort* Bt4  = (ushort*)(ws + 5139776);     // 1680*256 sh = 215040 fl -> 5354816
    float*  outp = (float*)d_out;

    k_front<<<9230, 256, 0, stream>>>(replay, ccw, ccb, fcw, fcb,
                                      w1, w2, w3, w4, whh,
                                      sca, wsum, sa, A2, A3, A4, whhT);
    k_cnn1<16><<<dim3(64, 64), 256, 0, stream>>>(sca, emb, w1, b1, wsum, sa, Bt2);
    // gemm1 (cnn2): M=512(482), K=1024(964), B rows 6400 -> Bt3 transposed bf16
    k_gemm_conv<482, 100, 98, 1024, 512, 2, 512, true, 8, 50>
        <<<400, 256, 0, stream>>>(A2, Bt2, b2, Bt3);
    // gemm2 (cnn3): M=256(241), K=512(482), B rows 3200 -> Bt4 transposed bf16
    k_gemm_conv<241, 50, 48, 512, 256, 2, 256, true, 4, 25>
        <<<100, 256, 0, stream>>>(A3, Bt3, b3, Bt4);
    // gemm3 (cnn4): M=128(100), K=256(241), B rows 1600, no pool -> z4 fp32
    k_gemm_conv<100, 25, 23, 256, 128, 0, 0, false, 2, 13>
        <<<26, 256, 0, stream>>>(A4, Bt4, b4, z4);
    k_seq_xg<<<64, 512, 0, stream>>>(z4, fcnw, fcnb, wih, bih, bhh, xg);
    k_lstm<<<2, 448, 0, stream>>>(xg, whhT, fow, fob, outp);
}

// Round 16
// 145.426 us; speedup vs baseline: 1.2770x; 1.2770x over previous
//
#include <hip/hip_runtime.h>
#include <math.h>

#define DEVFN __device__ __forceinline__

typedef __bf16 bf16x8 __attribute__((ext_vector_type(8)));
typedef float f32x4 __attribute__((ext_vector_type(4)));

constexpr int T_ = 32;
constexpr int HW = 128;
constexpr int C1IN = 1928;        // cnn1 input channels
constexpr int C1 = 964;

DEVFN float sigm(float x) { return 1.0f / (1.0f + __expf(-x)); }
DEVFN float tanhfast(float x) { return 2.0f / (1.0f + __expf(-2.0f * x)) - 1.0f; }

DEVFN ushort f2b(float v) {       // fp32 -> bf16 (RNE)
    union { float f; unsigned u; } x; x.f = v;
    unsigned r = x.u + 0x7fffu + ((x.u >> 16) & 1u);
    return (ushort)(r >> 16);
}

// async DMA global->LDS, 16B per lane (r8 lesson: zero staging VGPRs).
DEVFN void gload16(const ushort* g, ushort* l) {
    __builtin_amdgcn_global_load_lds(
        (const __attribute__((address_space(1))) unsigned int*)g,
        (__attribute__((address_space(3))) unsigned int*)l, 16, 0, 0);
}

// ---------------------------------------------------------------------------
// k_front: union grid of INDEPENDENT work (parallelism-preserving fusion):
//   blocks [0,5533):      weight prep A2/A3/A4/whhT
//   blocks [5533,5774):   wsum (4 oc/blk, wave-reduce)
//   blocks [5774,6030):   sa (n, oc)
//   blocks [6030,9230):   sca: per-(n, o-quad) block recomputes conv_con+
//                         relu+pool into LDS, then fc_con wave-reduce.
__global__ void k_front(const float* __restrict__ replay, const float* __restrict__ wc,
                        const float* __restrict__ bc, const float* __restrict__ fcw,
                        const float* __restrict__ fcb, const float* __restrict__ w1,
                        const float* __restrict__ w2, const float* __restrict__ w3,
                        const float* __restrict__ w4, const float* __restrict__ whh,
                        float* __restrict__ sca, float* __restrict__ wsum,
                        float* __restrict__ sa, ushort* __restrict__ A2,
                        ushort* __restrict__ A3, ushort* __restrict__ A4,
                        float* __restrict__ whhT) {
    const int bid = blockIdx.x;
    const int tx = threadIdx.x;
    constexpr int N2 = 2 * 512 * 1024;
    constexpr int N3 = 2 * 256 * 512;
    constexpr int N4 = 2 * 128 * 256;
    __shared__ __align__(16) float ys[961];
    if (bid < 5533) {
        const int idx = bid * 256 + tx;
        if (idx < N2) {
            const int kw = idx >> 19;
            const int r = idx & 524287;
            const int oc = r >> 10, ic = r & 1023;
            const float v = (oc < 482 && ic < 964) ? w2[(size_t)oc * 1928 + ic * 2 + kw] : 0.f;
            A2[idx] = f2b(v);
        } else if (idx < N2 + N3) {
            const int j = idx - N2;
            const int kw = j >> 17;
            const int r = j & 131071;
            const int oc = r >> 9, ic = r & 511;
            const float v = (oc < 241 && ic < 482) ? w3[(size_t)oc * 964 + ic * 2 + kw] : 0.f;
            A3[j] = f2b(v);
        } else if (idx < N2 + N3 + N4) {
            const int j = idx - (N2 + N3);
            const int kw = j >> 15;
            const int r = j & 32767;
            const int oc = r >> 8, ic = r & 255;
            const float v = (oc < 100 && ic < 241) ? w4[(size_t)oc * 482 + ic * 2 + kw] : 0.f;
            A4[j] = f2b(v);
        } else {
            const int j = idx - (N2 + N3 + N4);
            if (j < 40000) {
                const int m = j / 400, p = j - m * 400;
                const int go = (p & 3) * 100 + (p >> 2);
                whhT[m * 400 + p] = whh[go * 100 + m];
            }
        }
    } else if (bid < 5774) {
        const int oc = (bid - 5533) * 4 + (tx >> 6);       // < 964
        const int lane = tx & 63;
        const float* wr = w1 + (size_t)oc * C1IN * 2;
        float s0 = 0.f, s1 = 0.f;
        for (int ic = lane; ic < C1IN; ic += 64) {
            s0 += wr[ic * 2 + 0];
            s1 += wr[ic * 2 + 1];
        }
        #pragma unroll
        for (int off = 32; off > 0; off >>= 1) {
            s0 += __shfl_down(s0, off);
            s1 += __shfl_down(s1, off);
        }
        if (lane == 0) { wsum[oc * 2] = s0; wsum[oc * 2 + 1] = s1; }
    } else if (bid < 6030) {
        const int j = bid - 5774;                           // 0..255
        const int n = j >> 2;
        const int oc = (j & 3) * 256 + tx;
        if (oc < C1) {
            const int chs[5]    = {1, 3, 5, 6, 7};
            const int scales[5] = {4, 2, 5, 2, 1914};
            const int offs[5]   = {0, 4, 6, 11, 13};
            float s0 = 0.f, s1 = 0.f;
            #pragma unroll
            for (int k = 0; k < 5; ++k) {
                int v = (int)replay[((size_t)n * 8 + chs[k]) * HW * HW];
                if (v > scales[k]) v = 0;
                if (v >= 1 && v <= scales[k] - 1) {
                    const int ic = 1 + offs[k] + v;
                    s0 += w1[((size_t)oc * C1IN + ic) * 2 + 0];
                    s1 += w1[((size_t)oc * C1IN + ic) * 2 + 1];
                }
            }
            sa[(n * C1 + oc) * 2 + 0] = s0;
            sa[(n * C1 + oc) * 2 + 1] = s1;
        }
    } else {
        // sca blocks: sid in [0,3200) = 64 samples x 50 output-quads
        const int sid = bid - 6030;
        const int n = sid / 50;
        const int o0 = (sid - n * 50) * 4;
        const float* x = replay + (size_t)n * 8 * HW * HW;  // channel 0
        float wr_[16];
        #pragma unroll
        for (int t = 0; t < 16; ++t) wr_[t] = wc[t];
        const float bcv = bc[0];
        for (int idx = tx; idx < 961; idx += 256) {
            const int i = idx / 31, j = idx % 31;
            float m = 0.0f;
            #pragma unroll
            for (int di = 0; di < 2; ++di)
            #pragma unroll
            for (int dj = 0; dj < 2; ++dj) {
                const int h0 = 2 * (2 * i + di), w0 = 2 * (2 * j + dj);
                float acc = bcv;
                #pragma unroll
                for (int p = 0; p < 4; ++p)
                #pragma unroll
                for (int q = 0; q < 4; ++q)
                    acc += x[(h0 + p) * HW + (w0 + q)] * wr_[p * 4 + q];
                m = fmaxf(m, fmaxf(acc, 0.0f));
            }
            ys[idx] = m;
        }
        __syncthreads();
        const int wid = tx >> 6, lane = tx & 63;
        const int o = o0 + wid;                             // < 200
        float acc = 0.f;
        for (int m = lane; m < 961; m += 64)
            acc += ys[m] * fcw[(size_t)o * 961 + m];
        #pragma unroll
        for (int off = 32; off > 0; off >>= 1) acc += __shfl_down(acc, off);
        if (lane == 0) sca[n * 200 + o] = acc + fcb[o];
    }
}

// ---------------------------------------------------------------------------
// cnn1 low-rank decomposition + relu + pool(1,2), writes Bt2 (transposed,
// bf16): Bt2[(n*100 + u)][oc] = p1[n][oc][u] for u<99; u=99 zero pad row.
template <int OCT>
__global__ void k_cnn1(const float* __restrict__ sca, const float* __restrict__ emb,
                       const float* __restrict__ w1, const float* __restrict__ b1,
                       const float* __restrict__ wsum, const float* __restrict__ sa,
                       ushort* __restrict__ Bt2) {
    const int n = blockIdx.x;
    const int ocBase = blockIdx.y * OCT;
    const int tx = threadIdx.x;
    __shared__ float ev[200], sv[200], dv[200];
    __shared__ float oscal[OCT][7];
    __shared__ float vals[OCT][100];
    for (int i = tx; i < 200; i += blockDim.x) {
        const float e0 = emb[i], e1 = emb[200 + i];
        ev[i] = e0;
        dv[i] = e1 - e0;
        sv[i] = sca[n * 200 + i] - e0;
    }
    for (int i = tx; i < OCT * 7; i += blockDim.x) {
        const int ocl = i / 7, f = i % 7;
        const int oc = ocBase + ocl;
        float v = 0.f;
        if (oc < C1) {
            switch (f) {
                case 0: v = wsum[oc * 2 + 0]; break;
                case 1: v = wsum[oc * 2 + 1]; break;
                case 2: v = b1[oc]; break;
                case 3: v = w1[(size_t)oc * C1IN * 2 + 0]; break;
                case 4: v = w1[(size_t)oc * C1IN * 2 + 1]; break;
                case 5: v = sa[(n * C1 + oc) * 2 + 0]; break;
                case 6: v = sa[(n * C1 + oc) * 2 + 1]; break;
            }
        }
        oscal[ocl][f] = v;
    }
    __syncthreads();
    for (int item = tx; item < OCT * 99; item += blockDim.x) {
        const int ocl = item / 99, u = item % 99;
        const int oc = ocBase + ocl;
        float res = 0.f;
        if (oc < C1) {
            const float ws0 = oscal[ocl][0], ws1 = oscal[ocl][1], bb = oscal[ocl][2];
            const float a0 = oscal[ocl][3], a1 = oscal[ocl][4];
            const float s0 = oscal[ocl][5], s1 = oscal[ocl][6];
            float r = -INFINITY;
            #pragma unroll
            for (int dw = 0; dw < 2; ++dw) {
                const int ww = 2 * u + dw;
                const float o = bb + ws0 * ev[ww] + ws1 * ev[ww + 1]
                                   + a0 * sv[ww] + a1 * sv[ww + 1]
                                   + s0 * dv[ww] + s1 * dv[ww + 1];
                r = fmaxf(r, o);
            }
            res = fmaxf(r, 0.0f);
        }
        vals[ocl][u] = res;
    }
    __syncthreads();
    // transposed write: OCT ocs x 100 rows
    for (int i = tx; i < OCT * 100; i += blockDim.x) {
        const int u = i >> 4, ocl = i & 15;
        const float v = (u < 99) ? vals[ocl][u] : 0.0f;
        Bt2[(size_t)(n * 100 + u) * 1024 + ocBase + ocl] = f2b(v);
    }
    if (n == 0 && ocBase == 0) {
        for (int i = tx; i < 1024; i += blockDim.x)
            Bt2[(size_t)6400 * 1024 + i] = 0;
    }
}

// ---------------------------------------------------------------------------
// Conv-GEMM (w-shift): C[m][r] = sum_k A0[m][k]*Bt[r][k] + A1[m][k]*Bt[r+1][k]
// Tile 64(M)x128(N), BK=64, 4 waves, global_load_lds staging, double-buffered
// LDS with COUNTED vmcnt pipeline (T4), raw s_barrier, source-side XOR
// swizzle, bijective XCD swizzle.
//   OMODE 0: fp32 [n][OCREAL][NOUTW]; OMODE 2: bf16 transposed next-layer B.
template <int OCREAL, int WR, int WOUT, int KICP, int MPAD, int OMODE, int OSTR,
          bool POOL, int MT, int NTILES>
__global__ __launch_bounds__(256, 2) void k_gemm_conv(
    const ushort* __restrict__ A, const ushort* __restrict__ Bt,
    const float* __restrict__ bias, void* __restrict__ outv) {
    constexpr int BK = 64;
    constexpr int NT = KICP / BK;
    constexpr int NWG = MT * NTILES;
    constexpr int Qq = NWG / 8, Rr = NWG % 8;

    __shared__ __align__(16) ushort As0[2][4096];   // 64 rows x 64 (8 slabs)
    __shared__ __align__(16) ushort As1[2][4096];
    __shared__ __align__(16) ushort Bs[2][8704];    // 128(+1) rows (17 slabs)

    const int bid = blockIdx.x;
    const int xcd = bid & 7, rest = bid >> 3;
    const int base = (xcd < Rr) ? xcd * (Qq + 1) : Rr * (Qq + 1) + (xcd - Rr) * Qq;
    const int sid = base + rest;
    const int mBase = (sid % MT) * 64;
    const int nBase = (sid / MT) * 128;

    const int tx = threadIdx.x;
    const int wave = tx >> 6, lane = tx & 63;
    const int lr = lane & 15, lk = lane >> 4;
    const int r8 = lane >> 3;                        // within-slab row
    const int cx = (lane & 7) ^ r8;                  // swizzled source chunk
    const ushort* A1p = A + (size_t)MPAD * KICP;

    f32x4 acc[4][2] = {};

    auto STAGE = [&](int buf, int kt) {
        const int k0 = kt * BK + cx * 8;
        #pragma unroll
        for (int it = 0; it < 2; ++it) {
            const int s = wave + it * 4;             // slab 0..7
            const int row = s * 8 + r8;
            gload16(&A[(size_t)(mBase + row) * KICP + k0], &As0[buf][s * 512]);
            gload16(&A1p[(size_t)(mBase + row) * KICP + k0], &As1[buf][s * 512]);
        }
        #pragma unroll
        for (int it = 0; it < 4; ++it) {
            const int s = wave + it * 4;             // slab 0..15
            const int row = s * 8 + r8;
            gload16(&Bt[(size_t)(nBase + row) * KICP + k0], &Bs[buf][s * 512]);
        }
        if (wave == 0) {
            const int row = 128 + r8;                // strays inert in d_ws
            gload16(&Bt[(size_t)(nBase + row) * KICP + k0], &Bs[buf][16 * 512]);
        }
    };

    auto COMPUTE = [&](int cur) {
        #pragma unroll
        for (int ks = 0; ks < 2; ++ks) {
            bf16x8 a0[4], a1[4], b0[2], b1[2];
            #pragma unroll
            for (int i = 0; i < 4; ++i) {
                const int row = i * 16 + lr;
                const int col = (ks * 32 + lk * 8) ^ ((row & 7) << 3);
                a0[i] = *(const bf16x8*)&As0[cur][row * 64 + col];
                a1[i] = *(const bf16x8*)&As1[cur][row * 64 + col];
            }
            #pragma unroll
            for (int j = 0; j < 2; ++j) {
                const int row = wave * 32 + j * 16 + lr;
                const int col = (ks * 32 + lk * 8) ^ ((row & 7) << 3);
                b0[j] = *(const bf16x8*)&Bs[cur][row * 64 + col];
                const int row1 = row + 1;
                const int col1 = (ks * 32 + lk * 8) ^ ((row1 & 7) << 3);
                b1[j] = *(const bf16x8*)&Bs[cur][row1 * 64 + col1];
            }
            #pragma unroll
            for (int i = 0; i < 4; ++i)
                #pragma unroll
                for (int j = 0; j < 2; ++j) {
                    acc[i][j] = __builtin_amdgcn_mfma_f32_16x16x32_bf16(a0[i], b0[j], acc[i][j], 0, 0, 0);
                    acc[i][j] = __builtin_amdgcn_mfma_f32_16x16x32_bf16(a1[i], b1[j], acc[i][j], 0, 0, 0);
                }
        }
    };

    // 2-deep prologue
    STAGE(0, 0);
    if (NT > 1) STAGE(1, 1);
    #pragma unroll 1
    for (int kt = 0; kt < NT; ++kt) {
        const int cur = kt & 1;
        // wait for tile kt only (issued 2 steps ago); per-wave DMA count 9/8
        if (kt + 1 < NT) {
            if (wave == 0) asm volatile("s_waitcnt vmcnt(9)" ::: "memory");
            else           asm volatile("s_waitcnt vmcnt(8)" ::: "memory");
        } else {
            asm volatile("s_waitcnt vmcnt(0)" ::: "memory");
        }
        __builtin_amdgcn_sched_barrier(0);
        __builtin_amdgcn_s_barrier();                // tile kt resident block-wide
        COMPUTE(cur);
        __builtin_amdgcn_s_barrier();                // all reads of buf cur done
        if (kt + 2 < NT) STAGE(cur, kt + 2);         // overwrite cur, flies 2 steps
    }

    ushort* outb = (ushort*)outv;
    float*  outf = (float*)outv;
    constexpr int NOUTW = POOL ? (WOUT / 2) : WOUT;
    constexpr int WRN = NOUTW + 1;                   // rows/sample next layer
    constexpr int NVALID = WR * 64;
    #pragma unroll
    for (int i = 0; i < 4; ++i) {
        const int m0 = mBase + i * 16 + lk * 4;
        #pragma unroll
        for (int j = 0; j < 2; ++j) {
            const int r = nBase + wave * 32 + j * 16 + lr;
            const int n = r / WR, w = r - n * WR;
            #pragma unroll
            for (int reg = 0; reg < 4; ++reg) {
                const float v = acc[i][j][reg];
                const float vo = __shfl_xor(v, 1);
                const int m = m0 + reg;
                const bool lok = POOL ? ((lr & 1) == 0) : true;
                if (lok && (w < WOUT) && (m < OCREAL) && (r < NVALID)) {
                    const float pre = POOL ? fmaxf(v, vo) : v;
                    const float val = fmaxf(pre + bias[m], 0.0f);
                    const int wc = POOL ? (w >> 1) : w;
                    if (OMODE == 2)
                        outb[((size_t)(n * WRN + wc)) * OSTR + m] = f2b(val);
                    else
                        outf[((size_t)n * OCREAL + m) * NOUTW + wc] = val;
                }
            }
        }
    }
}

// ---------------------------------------------------------------------------
// fc_cnn: seq[n][o] = z4[n][2300] . W[o] + b[o]   (one wave per output;
// r15 lesson: the 64-block fused version was 74us latency-bound — keep the
// 1600-block width)
__global__ void k_fc_cnn(const float* __restrict__ z4, const float* __restrict__ w,
                         const float* __restrict__ b, float* __restrict__ seq) {
    const int n = blockIdx.x;
    const int wid = threadIdx.x >> 6, lane = threadIdx.x & 63;
    const int o = blockIdx.y * 4 + wid;                    // < 100
    const float4* zr = (const float4*)(z4 + (size_t)n * 2300);
    const float4* wr = (const float4*)(w + (size_t)o * 2300);
    float acc = 0.f;
    for (int m = lane; m < 575; m += 64) {
        const float4 wv = wr[m];
        const float4 zv = zr[m];
        acc += wv.x * zv.x + wv.y * zv.y + wv.z * zv.z + wv.w * zv.w;
    }
    #pragma unroll
    for (int off = 32; off > 0; off >>= 1) acc += __shfl_down(acc, off);
    if (lane == 0) seq[n * 100 + o] = acc + b[o];
}

// xg (PERMUTED gate layout p: gate=(p%4), unit=p/4) = seq @ W_ih.T + b_ih + b_hh
__global__ void k_xg(const float* __restrict__ seq, const float* __restrict__ wih,
                     const float* __restrict__ bih, const float* __restrict__ bhh,
                     float* __restrict__ xg) {
    const int n = blockIdx.x;
    __shared__ __align__(16) float s[100];
    if (threadIdx.x < 100) s[threadIdx.x] = seq[n * 100 + threadIdx.x];
    __syncthreads();
    const int p = threadIdx.x;
    if (p < 400) {
        const int go = (p & 3) * 100 + (p >> 2);
        const float4* wr = (const float4*)(wih + (size_t)go * 100);
        const float4* s4 = (const float4*)s;
        float4 a = {0.f, 0.f, 0.f, 0.f};
        #pragma unroll
        for (int m = 0; m < 25; ++m) {
            const float4 wv = wr[m];
            const float4 sv = s4[m];
            a.x += wv.x * sv.x; a.y += wv.y * sv.y;
            a.z += wv.z * sv.z; a.w += wv.w * sv.w;
        }
        xg[n * 400 + p] = bih[go] + bhh[go] + a.x + a.y + a.z + a.w;
    }
}

// ---------------------------------------------------------------------------
// LSTM: one block per batch. Per-quad distributed activations, fast tanh,
// 4-way split accumulators, 448 threads.
__global__ __launch_bounds__(448) void k_lstm(const float* __restrict__ xg,
                                              const float* __restrict__ whhT,
                                              const float* __restrict__ fw,
                                              const float* __restrict__ fb,
                                              float* __restrict__ outp) {
    const int bb = blockIdx.x;
    const int tx = threadIdx.x;
    __shared__ __align__(16) float hb[2][104];
    float wreg[100];
    if (tx < 400) {
        #pragma unroll
        for (int m = 0; m < 100; ++m) wreg[m] = whhT[m * 400 + tx];
    }
    float creg = 0.f;
    if (tx < 104) { hb[0][tx] = 0.f; hb[1][tx] = 0.f; }
    float xnext = (tx < 400) ? xg[(size_t)(bb * T_) * 400 + tx] : 0.f;
    __syncthreads();
    const int lane = tx & 63, base = lane & ~3;
    const int g = tx & 3;
    for (int t = 0; t < T_; ++t) {
        float act = 0.f;
        if (tx < 400) {
            float a0 = xnext, a1 = 0.f, a2 = 0.f, a3 = 0.f;
            if (t + 1 < T_) xnext = xg[(size_t)(bb * T_ + t + 1) * 400 + tx];
            const float4* h4 = (const float4*)&hb[t & 1][0];
            #pragma unroll
            for (int m4 = 0; m4 < 25; ++m4) {
                const float4 hv = h4[m4];
                a0 += hv.x * wreg[4 * m4 + 0];
                a1 += hv.y * wreg[4 * m4 + 1];
                a2 += hv.z * wreg[4 * m4 + 2];
                a3 += hv.w * wreg[4 * m4 + 3];
            }
            const float accv = (a0 + a1) + (a2 + a3);
            act = (g == 2) ? tanhfast(accv) : sigm(accv);  // own gate only
        }
        const float aI = __shfl(act, base + 0);
        const float aF = __shfl(act, base + 1);
        const float aG = __shfl(act, base + 2);
        const float aO = __shfl(act, base + 3);
        if (tx < 400) {
            const float cn = aF * creg + aI * aG;
            creg = cn;
            if (g == 0) hb[(t + 1) & 1][tx >> 2] = aO * tanhfast(cn);
        }
        __syncthreads();
    }
    if (tx < 2) {
        float acc = fb[tx];
        for (int j = 0; j < 100; ++j) acc += hb[0][j] * fw[tx * 100 + j];
        outp[bb * 2 + tx] = acc;
    }
}

// ---------------------------------------------------------------------------
extern "C" void kernel_launch(void* const* d_in, const int* in_sizes, int n_in,
                              void* d_out, int out_size, void* d_ws, size_t ws_size,
                              hipStream_t stream) {
    (void)in_sizes; (void)n_in; (void)out_size; (void)ws_size;
    const float* replay = (const float*)d_in[0];
    const float* emb    = (const float*)d_in[1];
    const float* ccw    = (const float*)d_in[2];
    const float* ccb    = (const float*)d_in[3];
    const float* fcw    = (const float*)d_in[4];
    const float* fcb    = (const float*)d_in[5];
    const float* w1     = (const float*)d_in[6];
    const float* b1     = (const float*)d_in[7];
    const float* w2     = (const float*)d_in[8];
    const float* b2     = (const float*)d_in[9];
    const float* w3     = (const float*)d_in[10];
    const float* b3     = (const float*)d_in[11];
    const float* w4     = (const float*)d_in[12];
    const float* b4     = (const float*)d_in[13];
    const float* fcnw   = (const float*)d_in[14];
    const float* fcnb   = (const float*)d_in[15];
    const float* wih    = (const float*)d_in[16];
    const float* whh    = (const float*)d_in[17];
    const float* bih    = (const float*)d_in[18];
    const float* bhh    = (const float*)d_in[19];
    const float* fow    = (const float*)d_in[20];
    const float* fob    = (const float*)d_in[21];

    float* ws = (float*)d_ws;
    float*  sca  = ws + 0;                      // 12800
    float*  wsum = ws + 12800;                  // 2048
    float*  sa   = ws + 14848;                  // 123392 -> 138240
    float*  seq  = ws + 138240;                 // 6400 -> 144640
    float*  xg   = ws + 144640;                 // 25600 -> 170240
    float*  whhT = ws + 170240;                 // 40000 -> 210240
    float*  z4   = ws + 210240;                 // 147200 -> 357440
    ushort* A2   = (ushort*)(ws + 357440);      // 524288 fl -> 881728
    ushort* A3   = (ushort*)(ws + 881728);      // 131072 fl -> 1012800
    ushort* A4   = (ushort*)(ws + 1012800);     // 32768 fl -> 1045568
    ushort* Bt2  = (ushort*)(ws + 1045568);     // 6401*1024 sh = 3277312 fl -> 4322880
    ushort* Bt3  = (ushort*)(ws + 4322880);     // 3216*512 sh = 823296 fl -> 5146176
    ushort* Bt4  = (ushort*)(ws + 5146176);     // 1680*256 sh = 215040 fl -> 5361216
    float*  outp = (float*)d_out;

    k_front<<<9230, 256, 0, stream>>>(replay, ccw, ccb, fcw, fcb,
                                      w1, w2, w3, w4, whh,
                                      sca, wsum, sa, A2, A3, A4, whhT);
    k_cnn1<16><<<dim3(64, 64), 256, 0, stream>>>(sca, emb, w1, b1, wsum, sa, Bt2);
    // gemm1 (cnn2): M=512(482), K=1024(964), B rows 6400 -> Bt3 transposed bf16
    k_gemm_conv<482, 100, 98, 1024, 512, 2, 512, true, 8, 50>
        <<<400, 256, 0, stream>>>(A2, Bt2, b2, Bt3);
    // gemm2 (cnn3): M=256(241), K=512(482), B rows 3200 -> Bt4 transposed bf16
    k_gemm_conv<241, 50, 48, 512, 256, 2, 256, true, 4, 25>
        <<<100, 256, 0, stream>>>(A3, Bt3, b3, Bt4);
    // gemm3 (cnn4): M=128(100), K=256(241), B rows 1600, no pool -> z4 fp32
    k_gemm_conv<100, 25, 23, 256, 128, 0, 0, false, 2, 13>
        <<<26, 256, 0, stream>>>(A4, Bt4, b4, z4);
    k_fc_cnn<<<dim3(64, 25), 256, 0, stream>>>(z4, fcnw, fcnb, seq);
    k_xg<<<64, 512, 0, stream>>>(seq, wih, bih, bhh, xg);
    k_lstm<<<2, 448, 0, stream>>>(xg, whhT, fow, fob, outp);
}

// Round 17
// 136.876 us; speedup vs baseline: 1.3568x; 1.0625x over previous
//
#include <hip/hip_runtime.h>
#include <math.h>

#define DEVFN __device__ __forceinline__

typedef __bf16 bf16x8 __attribute__((ext_vector_type(8)));
typedef float f32x4 __attribute__((ext_vector_type(4)));

constexpr int T_ = 32;
constexpr int HW = 128;
constexpr int C1IN = 1928;        // cnn1 input channels
constexpr int C1 = 964;

DEVFN float sigm(float x) { return 1.0f / (1.0f + __expf(-x)); }
DEVFN float tanhfast(float x) { return 2.0f / (1.0f + __expf(-2.0f * x)) - 1.0f; }

DEVFN ushort f2b(float v) {       // fp32 -> bf16 (RNE)
    union { float f; unsigned u; } x; x.f = v;
    unsigned r = x.u + 0x7fffu + ((x.u >> 16) & 1u);
    return (ushort)(r >> 16);
}

// async DMA global->LDS, 16B per lane (r8 lesson: zero staging VGPRs).
DEVFN void gload16(const ushort* g, ushort* l) {
    __builtin_amdgcn_global_load_lds(
        (const __attribute__((address_space(1))) unsigned int*)g,
        (__attribute__((address_space(3))) unsigned int*)l, 16, 0, 0);
}

// ---------------------------------------------------------------------------
// k_front: union grid of INDEPENDENT work, NO redundant compute (r16 lesson:
// recomputing conv 50x to kill a boundary cost 12us to save 5):
//   blocks [0,256):       conv_con+relu+pool -> yb[n][961]  (n=bid>>2)
//   blocks [256,5789):    weight prep A2/A3/A4/whhT
//   blocks [5789,6030):   wsum (4 oc/blk, wave-reduce)
//   blocks [6030,6286):   sa (n, oc)
__global__ void k_front(const float* __restrict__ replay, const float* __restrict__ wc,
                        const float* __restrict__ bc, const float* __restrict__ w1,
                        const float* __restrict__ w2, const float* __restrict__ w3,
                        const float* __restrict__ w4, const float* __restrict__ whh,
                        float* __restrict__ yb, float* __restrict__ wsum,
                        float* __restrict__ sa, ushort* __restrict__ A2,
                        ushort* __restrict__ A3, ushort* __restrict__ A4,
                        float* __restrict__ whhT) {
    const int bid = blockIdx.x;
    const int tx = threadIdx.x;
    constexpr int N2 = 2 * 512 * 1024;
    constexpr int N3 = 2 * 256 * 512;
    constexpr int N4 = 2 * 128 * 256;
    if (bid < 256) {
        const int n = bid >> 2;
        const int idx = (bid & 3) * 256 + tx;
        if (idx >= 961) return;
        const float* x = replay + (size_t)n * 8 * HW * HW;     // channel 0
        float wr_[16];
        #pragma unroll
        for (int t = 0; t < 16; ++t) wr_[t] = wc[t];
        const float bcv = bc[0];
        const int i = idx / 31, j = idx % 31;
        float m = 0.0f;
        #pragma unroll
        for (int di = 0; di < 2; ++di)
        #pragma unroll
        for (int dj = 0; dj < 2; ++dj) {
            const int h0 = 2 * (2 * i + di), w0 = 2 * (2 * j + dj);
            float acc = bcv;
            #pragma unroll
            for (int p = 0; p < 4; ++p)
            #pragma unroll
            for (int q = 0; q < 4; ++q)
                acc += x[(h0 + p) * HW + (w0 + q)] * wr_[p * 4 + q];
            m = fmaxf(m, fmaxf(acc, 0.0f));
        }
        yb[n * 961 + idx] = m;
    } else if (bid < 256 + 5533) {
        const int idx = (bid - 256) * 256 + tx;
        if (idx < N2) {
            const int kw = idx >> 19;
            const int r = idx & 524287;
            const int oc = r >> 10, ic = r & 1023;
            const float v = (oc < 482 && ic < 964) ? w2[(size_t)oc * 1928 + ic * 2 + kw] : 0.f;
            A2[idx] = f2b(v);
        } else if (idx < N2 + N3) {
            const int j = idx - N2;
            const int kw = j >> 17;
            const int r = j & 131071;
            const int oc = r >> 9, ic = r & 511;
            const float v = (oc < 241 && ic < 482) ? w3[(size_t)oc * 964 + ic * 2 + kw] : 0.f;
            A3[j] = f2b(v);
        } else if (idx < N2 + N3 + N4) {
            const int j = idx - (N2 + N3);
            const int kw = j >> 15;
            const int r = j & 32767;
            const int oc = r >> 8, ic = r & 255;
            const float v = (oc < 100 && ic < 241) ? w4[(size_t)oc * 482 + ic * 2 + kw] : 0.f;
            A4[j] = f2b(v);
        } else {
            const int j = idx - (N2 + N3 + N4);
            if (j < 40000) {
                const int m = j / 400, p = j - m * 400;
                const int go = (p & 3) * 100 + (p >> 2);
                whhT[m * 400 + p] = whh[go * 100 + m];
            }
        }
    } else if (bid < 256 + 5774) {
        const int oc = (bid - (256 + 5533)) * 4 + (tx >> 6);   // < 964
        const int lane = tx & 63;
        const float* wr = w1 + (size_t)oc * C1IN * 2;
        float s0 = 0.f, s1 = 0.f;
        for (int ic = lane; ic < C1IN; ic += 64) {
            s0 += wr[ic * 2 + 0];
            s1 += wr[ic * 2 + 1];
        }
        #pragma unroll
        for (int off = 32; off > 0; off >>= 1) {
            s0 += __shfl_down(s0, off);
            s1 += __shfl_down(s1, off);
        }
        if (lane == 0) { wsum[oc * 2] = s0; wsum[oc * 2 + 1] = s1; }
    } else if (bid < 256 + 6030) {
        const int j = bid - (256 + 5774);                       // 0..255
        const int n = j >> 2;
        const int oc = (j & 3) * 256 + tx;
        if (oc < C1) {
            const int chs[5]    = {1, 3, 5, 6, 7};
            const int scales[5] = {4, 2, 5, 2, 1914};
            const int offs[5]   = {0, 4, 6, 11, 13};
            float s0 = 0.f, s1 = 0.f;
            #pragma unroll
            for (int k = 0; k < 5; ++k) {
                int v = (int)replay[((size_t)n * 8 + chs[k]) * HW * HW];
                if (v > scales[k]) v = 0;
                if (v >= 1 && v <= scales[k] - 1) {
                    const int ic = 1 + offs[k] + v;
                    s0 += w1[((size_t)oc * C1IN + ic) * 2 + 0];
                    s1 += w1[((size_t)oc * C1IN + ic) * 2 + 1];
                }
            }
            sa[(n * C1 + oc) * 2 + 0] = s0;
            sa[(n * C1 + oc) * 2 + 1] = s1;
        }
    }
}

// ---------------------------------------------------------------------------
// fc_con: sca[n][o] = yb[n] . fcw[o] + fcb[o]   (one wave per output)
__global__ void k_sca_fc(const float* __restrict__ y, const float* __restrict__ fcw,
                         const float* __restrict__ fcb, float* __restrict__ sca) {
    const int n = blockIdx.x;
    const int wid = threadIdx.x >> 6, lane = threadIdx.x & 63;
    const int o = blockIdx.y * 4 + wid;                    // < 200
    float acc = 0.f;
    for (int m = lane; m < 961; m += 64)
        acc += y[n * 961 + m] * fcw[(size_t)o * 961 + m];
    #pragma unroll
    for (int off = 32; off > 0; off >>= 1) acc += __shfl_down(acc, off);
    if (lane == 0) sca[n * 200 + o] = acc + fcb[o];
}

// ---------------------------------------------------------------------------
// cnn1 low-rank decomposition + relu + pool(1,2), writes Bt2 (transposed,
// bf16): Bt2[(n*100 + u)][oc] = p1[n][oc][u] for u<99; u=99 zero pad row.
template <int OCT>
__global__ void k_cnn1(const float* __restrict__ sca, const float* __restrict__ emb,
                       const float* __restrict__ w1, const float* __restrict__ b1,
                       const float* __restrict__ wsum, const float* __restrict__ sa,
                       ushort* __restrict__ Bt2) {
    const int n = blockIdx.x;
    const int ocBase = blockIdx.y * OCT;
    const int tx = threadIdx.x;
    __shared__ float ev[200], sv[200], dv[200];
    __shared__ float oscal[OCT][7];
    __shared__ float vals[OCT][100];
    for (int i = tx; i < 200; i += blockDim.x) {
        const float e0 = emb[i], e1 = emb[200 + i];
        ev[i] = e0;
        dv[i] = e1 - e0;
        sv[i] = sca[n * 200 + i] - e0;
    }
    for (int i = tx; i < OCT * 7; i += blockDim.x) {
        const int ocl = i / 7, f = i % 7;
        const int oc = ocBase + ocl;
        float v = 0.f;
        if (oc < C1) {
            switch (f) {
                case 0: v = wsum[oc * 2 + 0]; break;
                case 1: v = wsum[oc * 2 + 1]; break;
                case 2: v = b1[oc]; break;
                case 3: v = w1[(size_t)oc * C1IN * 2 + 0]; break;
                case 4: v = w1[(size_t)oc * C1IN * 2 + 1]; break;
                case 5: v = sa[(n * C1 + oc) * 2 + 0]; break;
                case 6: v = sa[(n * C1 + oc) * 2 + 1]; break;
            }
        }
        oscal[ocl][f] = v;
    }
    __syncthreads();
    for (int item = tx; item < OCT * 99; item += blockDim.x) {
        const int ocl = item / 99, u = item % 99;
        const int oc = ocBase + ocl;
        float res = 0.f;
        if (oc < C1) {
            const float ws0 = oscal[ocl][0], ws1 = oscal[ocl][1], bb = oscal[ocl][2];
            const float a0 = oscal[ocl][3], a1 = oscal[ocl][4];
            const float s0 = oscal[ocl][5], s1 = oscal[ocl][6];
            float r = -INFINITY;
            #pragma unroll
            for (int dw = 0; dw < 2; ++dw) {
                const int ww = 2 * u + dw;
                const float o = bb + ws0 * ev[ww] + ws1 * ev[ww + 1]
                                   + a0 * sv[ww] + a1 * sv[ww + 1]
                                   + s0 * dv[ww] + s1 * dv[ww + 1];
                r = fmaxf(r, o);
            }
            res = fmaxf(r, 0.0f);
        }
        vals[ocl][u] = res;
    }
    __syncthreads();
    // transposed write: OCT ocs x 100 rows
    for (int i = tx; i < OCT * 100; i += blockDim.x) {
        const int u = i >> 4, ocl = i & 15;
        const float v = (u < 99) ? vals[ocl][u] : 0.0f;
        Bt2[(size_t)(n * 100 + u) * 1024 + ocBase + ocl] = f2b(v);
    }
    if (n == 0 && ocBase == 0) {
        for (int i = tx; i < 1024; i += blockDim.x)
            Bt2[(size_t)6400 * 1024 + i] = 0;
    }
}

// ---------------------------------------------------------------------------
// Conv-GEMM (w-shift): C[m][r] = sum_k A0[m][k]*Bt[r][k] + A1[m][k]*Bt[r+1][k]
// Tile 64(M)x128(N), BK=64, 4 waves, global_load_lds staging, double-buffered
// LDS with COUNTED vmcnt pipeline (T4): tiles staged 2 deep; per K-step wait
// only for the tile about to be computed (wave0 issues 9 DMAs/stage, others 8
// -> per-wave immediates), raw s_barrier (no drain). Source-side XOR swizzle,
// bijective XCD swizzle.
//   OMODE 0: fp32 [n][OCREAL][NOUTW]; OMODE 2: bf16 transposed next-layer B.
template <int OCREAL, int WR, int WOUT, int KICP, int MPAD, int OMODE, int OSTR,
          bool POOL, int MT, int NTILES>
__global__ __launch_bounds__(256, 2) void k_gemm_conv(
    const ushort* __restrict__ A, const ushort* __restrict__ Bt,
    const float* __restrict__ bias, void* __restrict__ outv) {
    constexpr int BK = 64;
    constexpr int NT = KICP / BK;
    constexpr int NWG = MT * NTILES;
    constexpr int Qq = NWG / 8, Rr = NWG % 8;

    __shared__ __align__(16) ushort As0[2][4096];   // 64 rows x 64 (8 slabs)
    __shared__ __align__(16) ushort As1[2][4096];
    __shared__ __align__(16) ushort Bs[2][8704];    // 128(+1) rows (17 slabs)

    const int bid = blockIdx.x;
    const int xcd = bid & 7, rest = bid >> 3;
    const int base = (xcd < Rr) ? xcd * (Qq + 1) : Rr * (Qq + 1) + (xcd - Rr) * Qq;
    const int sid = base + rest;
    const int mBase = (sid % MT) * 64;
    const int nBase = (sid / MT) * 128;

    const int tx = threadIdx.x;
    const int wave = tx >> 6, lane = tx & 63;
    const int lr = lane & 15, lk = lane >> 4;
    const int r8 = lane >> 3;                        // within-slab row
    const int cx = (lane & 7) ^ r8;                  // swizzled source chunk
    const ushort* A1p = A + (size_t)MPAD * KICP;

    f32x4 acc[4][2] = {};

    auto STAGE = [&](int buf, int kt) {
        const int k0 = kt * BK + cx * 8;
        #pragma unroll
        for (int it = 0; it < 2; ++it) {
            const int s = wave + it * 4;             // slab 0..7
            const int row = s * 8 + r8;
            gload16(&A[(size_t)(mBase + row) * KICP + k0], &As0[buf][s * 512]);
            gload16(&A1p[(size_t)(mBase + row) * KICP + k0], &As1[buf][s * 512]);
        }
        #pragma unroll
        for (int it = 0; it < 4; ++it) {
            const int s = wave + it * 4;             // slab 0..15
            const int row = s * 8 + r8;
            gload16(&Bt[(size_t)(nBase + row) * KICP + k0], &Bs[buf][s * 512]);
        }
        if (wave == 0) {
            const int row = 128 + r8;                // strays inert in d_ws
            gload16(&Bt[(size_t)(nBase + row) * KICP + k0], &Bs[buf][16 * 512]);
        }
    };

    auto COMPUTE = [&](int cur) {
        #pragma unroll
        for (int ks = 0; ks < 2; ++ks) {
            bf16x8 a0[4], a1[4], b0[2], b1[2];
            #pragma unroll
            for (int i = 0; i < 4; ++i) {
                const int row = i * 16 + lr;
                const int col = (ks * 32 + lk * 8) ^ ((row & 7) << 3);
                a0[i] = *(const bf16x8*)&As0[cur][row * 64 + col];
                a1[i] = *(const bf16x8*)&As1[cur][row * 64 + col];
            }
            #pragma unroll
            for (int j = 0; j < 2; ++j) {
                const int row = wave * 32 + j * 16 + lr;
                const int col = (ks * 32 + lk * 8) ^ ((row & 7) << 3);
                b0[j] = *(const bf16x8*)&Bs[cur][row * 64 + col];
                const int row1 = row + 1;
                const int col1 = (ks * 32 + lk * 8) ^ ((row1 & 7) << 3);
                b1[j] = *(const bf16x8*)&Bs[cur][row1 * 64 + col1];
            }
            #pragma unroll
            for (int i = 0; i < 4; ++i)
                #pragma unroll
                for (int j = 0; j < 2; ++j) {
                    acc[i][j] = __builtin_amdgcn_mfma_f32_16x16x32_bf16(a0[i], b0[j], acc[i][j], 0, 0, 0);
                    acc[i][j] = __builtin_amdgcn_mfma_f32_16x16x32_bf16(a1[i], b1[j], acc[i][j], 0, 0, 0);
                }
        }
    };

    // 2-deep prologue
    STAGE(0, 0);
    if (NT > 1) STAGE(1, 1);
    #pragma unroll 1
    for (int kt = 0; kt < NT; ++kt) {
        const int cur = kt & 1;
        // wait for tile kt only (issued 2 steps ago); per-wave DMA count 9/8
        if (kt + 1 < NT) {
            if (wave == 0) asm volatile("s_waitcnt vmcnt(9)" ::: "memory");
            else           asm volatile("s_waitcnt vmcnt(8)" ::: "memory");
        } else {
            asm volatile("s_waitcnt vmcnt(0)" ::: "memory");
        }
        __builtin_amdgcn_sched_barrier(0);
        __builtin_amdgcn_s_barrier();                // tile kt resident block-wide
        COMPUTE(cur);
        __builtin_amdgcn_s_barrier();                // all reads of buf cur done
        if (kt + 2 < NT) STAGE(cur, kt + 2);         // overwrite cur, flies 2 steps
    }

    ushort* outb = (ushort*)outv;
    float*  outf = (float*)outv;
    constexpr int NOUTW = POOL ? (WOUT / 2) : WOUT;
    constexpr int WRN = NOUTW + 1;                   // rows/sample next layer
    constexpr int NVALID = WR * 64;
    #pragma unroll
    for (int i = 0; i < 4; ++i) {
        const int m0 = mBase + i * 16 + lk * 4;
        #pragma unroll
        for (int j = 0; j < 2; ++j) {
            const int r = nBase + wave * 32 + j * 16 + lr;
            const int n = r / WR, w = r - n * WR;
            #pragma unroll
            for (int reg = 0; reg < 4; ++reg) {
                const float v = acc[i][j][reg];
                const float vo = __shfl_xor(v, 1);
                const int m = m0 + reg;
                const bool lok = POOL ? ((lr & 1) == 0) : true;
                if (lok && (w < WOUT) && (m < OCREAL) && (r < NVALID)) {
                    const float pre = POOL ? fmaxf(v, vo) : v;
                    const float val = fmaxf(pre + bias[m], 0.0f);
                    const int wc = POOL ? (w >> 1) : w;
                    if (OMODE == 2)
                        outb[((size_t)(n * WRN + wc)) * OSTR + m] = f2b(val);
                    else
                        outf[((size_t)n * OCREAL + m) * NOUTW + wc] = val;
                }
            }
        }
    }
}

// ---------------------------------------------------------------------------
// fc_cnn: seq[n][o] = z4[n][2300] . W[o] + b[o]   (one wave per output)
__global__ void k_fc_cnn(const float* __restrict__ z4, const float* __restrict__ w,
                         const float* __restrict__ b, float* __restrict__ seq) {
    const int n = blockIdx.x;
    const int wid = threadIdx.x >> 6, lane = threadIdx.x & 63;
    const int o = blockIdx.y * 4 + wid;                    // < 100
    const float4* zr = (const float4*)(z4 + (size_t)n * 2300);
    const float4* wr = (const float4*)(w + (size_t)o * 2300);
    float acc = 0.f;
    for (int m = lane; m < 575; m += 64) {
        const float4 wv = wr[m];
        const float4 zv = zr[m];
        acc += wv.x * zv.x + wv.y * zv.y + wv.z * zv.z + wv.w * zv.w;
    }
    #pragma unroll
    for (int off = 32; off > 0; off >>= 1) acc += __shfl_down(acc, off);
    if (lane == 0) seq[n * 100 + o] = acc + b[o];
}

// xg (PERMUTED gate layout p: gate=(p%4), unit=p/4) = seq @ W_ih.T + b_ih + b_hh
__global__ void k_xg(const float* __restrict__ seq, const float* __restrict__ wih,
                     const float* __restrict__ bih, const float* __restrict__ bhh,
                     float* __restrict__ xg) {
    const int n = blockIdx.x;
    __shared__ __align__(16) float s[100];
    if (threadIdx.x < 100) s[threadIdx.x] = seq[n * 100 + threadIdx.x];
    __syncthreads();
    const int p = threadIdx.x;
    if (p < 400) {
        const int go = (p & 3) * 100 + (p >> 2);
        const float4* wr = (const float4*)(wih + (size_t)go * 100);
        const float4* s4 = (const float4*)s;
        float4 a = {0.f, 0.f, 0.f, 0.f};
        #pragma unroll
        for (int m = 0; m < 25; ++m) {
            const float4 wv = wr[m];
            const float4 sv = s4[m];
            a.x += wv.x * sv.x; a.y += wv.y * sv.y;
            a.z += wv.z * sv.z; a.w += wv.w * sv.w;
        }
        xg[n * 400 + p] = bih[go] + bhh[go] + a.x + a.y + a.z + a.w;
    }
}

// LSTM: one block per batch. Per-quad distributed activations (1 transc
// per thread per phase instead of 5), fast tanh via __expf, 4-way split
// accumulators (chain 100 -> 25), 448 threads (7 waves).
__global__ __launch_bounds__(448) void k_lstm(const float* __restrict__ xg,
                                              const float* __restrict__ whhT,
                                              const float* __restrict__ fw,
                                              const float* __restrict__ fb,
                                              float* __restrict__ outp) {
    const int bb = blockIdx.x;
    const int tx = threadIdx.x;
    __shared__ __align__(16) float hb[2][104];
    float wreg[100];
    if (tx < 400) {
        #pragma unroll
        for (int m = 0; m < 100; ++m) wreg[m] = whhT[m * 400 + tx];
    }
    float creg = 0.f;
    if (tx < 104) { hb[0][tx] = 0.f; hb[1][tx] = 0.f; }
    float xnext = (tx < 400) ? xg[(size_t)(bb * T_) * 400 + tx] : 0.f;
    __syncthreads();
    const int lane = tx & 63, base = lane & ~3;
    const int g = tx & 3;
    for (int t = 0; t < T_; ++t) {
        float act = 0.f;
        if (tx < 400) {
            float a0 = xnext, a1 = 0.f, a2 = 0.f, a3 = 0.f;
            if (t + 1 < T_) xnext = xg[(size_t)(bb * T_ + t + 1) * 400 + tx];
            const float4* h4 = (const float4*)&hb[t & 1][0];
            #pragma unroll
            for (int m4 = 0; m4 < 25; ++m4) {
                const float4 hv = h4[m4];
                a0 += hv.x * wreg[4 * m4 + 0];
                a1 += hv.y * wreg[4 * m4 + 1];
                a2 += hv.z * wreg[4 * m4 + 2];
                a3 += hv.w * wreg[4 * m4 + 3];
            }
            const float accv = (a0 + a1) + (a2 + a3);
            act = (g == 2) ? tanhfast(accv) : sigm(accv);  // own gate only
        }
        const float aI = __shfl(act, base + 0);
        const float aF = __shfl(act, base + 1);
        const float aG = __shfl(act, base + 2);
        const float aO = __shfl(act, base + 3);
        if (tx < 400) {
            const float cn = aF * creg + aI * aG;
            creg = cn;
            if (g == 0) hb[(t + 1) & 1][tx >> 2] = aO * tanhfast(cn);
        }
        __syncthreads();
    }
    if (tx < 2) {
        float acc = fb[tx];
        for (int j = 0; j < 100; ++j) acc += hb[0][j] * fw[tx * 100 + j];
        outp[bb * 2 + tx] = acc;
    }
}

// ---------------------------------------------------------------------------
extern "C" void kernel_launch(void* const* d_in, const int* in_sizes, int n_in,
                              void* d_out, int out_size, void* d_ws, size_t ws_size,
                              hipStream_t stream) {
    (void)in_sizes; (void)n_in; (void)out_size; (void)ws_size;
    const float* replay = (const float*)d_in[0];
    const float* emb    = (const float*)d_in[1];
    const float* ccw    = (const float*)d_in[2];
    const float* ccb    = (const float*)d_in[3];
    const float* fcw    = (const float*)d_in[4];
    const float* fcb    = (const float*)d_in[5];
    const float* w1     = (const float*)d_in[6];
    const float* b1     = (const float*)d_in[7];
    const float* w2     = (const float*)d_in[8];
    const float* b2     = (const float*)d_in[9];
    const float* w3     = (const float*)d_in[10];
    const float* b3     = (const float*)d_in[11];
    const float* w4     = (const float*)d_in[12];
    const float* b4     = (const float*)d_in[13];
    const float* fcnw   = (const float*)d_in[14];
    const float* fcnb   = (const float*)d_in[15];
    const float* wih    = (const float*)d_in[16];
    const float* whh    = (const float*)d_in[17];
    const float* bih    = (const float*)d_in[18];
    const float* bhh    = (const float*)d_in[19];
    const float* fow    = (const float*)d_in[20];
    const float* fob    = (const float*)d_in[21];

    float* ws = (float*)d_ws;
    float*  sca  = ws + 0;                      // 12800
    float*  wsum = ws + 12800;                  // 2048
    float*  sa   = ws + 14848;                  // 123392 -> 138240
    float*  seq  = ws + 138240;                 // 6400
    float*  xg   = ws + 144640;                 // 25600
    float*  whhT = ws + 170240;                 // 40000 -> 210240
    float*  yb   = ws + 210240;                 // 61504 -> pad 272384
    float*  z4   = ws + 272384;                 // 147200 -> 419584
    ushort* A2   = (ushort*)(ws + 419584);      // 2*512*1024 sh = 524288 fl -> 943872
    ushort* A3   = (ushort*)(ws + 943872);      // 2*256*512 sh = 131072 fl -> 1074944
    ushort* A4   = (ushort*)(ws + 1074944);     // 2*128*256 sh = 32768 fl -> 1107712
    ushort* Bt2  = (ushort*)(ws + 1107712);     // 6401*1024 sh = 3277312 fl -> 4385024
    ushort* Bt3  = (ushort*)(ws + 4385024);     // 3216*512 sh = 823296 fl -> 5208320
    ushort* Bt4  = (ushort*)(ws + 5208320);     // 1680*256 sh = 215040 fl -> 5423360
    float*  outp = (float*)d_out;

    k_front<<<6286, 256, 0, stream>>>(replay, ccw, ccb, w1, w2, w3, w4, whh,
                                      yb, wsum, sa, A2, A3, A4, whhT);
    k_sca_fc<<<dim3(64, 50), 256, 0, stream>>>(yb, fcw, fcb, sca);
    k_cnn1<16><<<dim3(64, 64), 256, 0, stream>>>(sca, emb, w1, b1, wsum, sa, Bt2);
    // gemm1 (cnn2): M=512(482), K=1024(964), B rows 6400 -> Bt3 transposed bf16
    k_gemm_conv<482, 100, 98, 1024, 512, 2, 512, true, 8, 50>
        <<<400, 256, 0, stream>>>(A2, Bt2, b2, Bt3);
    // gemm2 (cnn3): M=256(241), K=512(482), B rows 3200 -> Bt4 transposed bf16
    k_gemm_conv<241, 50, 48, 512, 256, 2, 256, true, 4, 25>
        <<<100, 256, 0, stream>>>(A3, Bt3, b3, Bt4);
    // gemm3 (cnn4): M=128(100), K=256(241), B rows 1600, no pool -> z4 fp32
    k_gemm_conv<100, 25, 23, 256, 128, 0, 0, false, 2, 13>
        <<<26, 256, 0, stream>>>(A4, Bt4, b4, z4);
    k_fc_cnn<<<dim3(64, 25), 256, 0, stream>>>(z4, fcnw, fcnb, seq);
    k_xg<<<64, 512, 0, stream>>>(seq, wih, bih, bhh, xg);
    k_lstm<<<2, 448, 0, stream>>>(xg, whhT, fow, fob, outp);
}